// Round 6
// baseline (392.951 us; speedup 1.0000x reference)
//
#include <hip/hip_runtime.h>
#include <hip/hip_bf16.h>
#include <math.h>

// GRU policy: B=2048, T=512, V=4, E=64, H=128.
// R5: (1) r,z sigmoids via 512-entry piecewise-linear LDS LUT (6 full-rate
//         VALU + 1 ds_read_b64 each) -> removes 16 of 24 trans/lane-step;
//         n's tanh stays on exp2/rcp (keeps the r->np->n serial tail short).
//     (2) b_hh_n*2log2e folded in as the a2 MFMA chain's C-init.
//     (3) a0/a1 as depth-3 dual chains + merge (shorter path to gate VALU).
//     (4) antiphase removed (R4 proved it neutral).
// Per wave/step: 15 MFMA, 4 ds_read_b128 + 1 ds_read_b64 + 8 LUT ds_read_b64
// + 1 ds_write_b64, 8 trans. 1 barrier/step. 128 blocks (structural: B/16).

#define B_  2048
#define T_  512
#define V_  4
#define E_  64
#define H_  128
#define G3  384
#define SH  136            // h row stride (bf16 elems)
#define TC  128            // timestep chunk for one-hot staging
#define ZIDX (TC * 16)     // zero slot index in ohbuf

#define LOG2E 1.4426950408889634f
// sigmoid LUT: u in [-9,9), 512 intervals
#define LUTN   512
#define LSCALE (512.f / 18.f)      // idx = (u + 9) * LSCALE
#define LOFF   256.f
#define UCLMIN -9.0f
#define UCLMAX  8.999f             // keeps idx <= 511

typedef __attribute__((ext_vector_type(8))) short  short8;   // 8 bf16
typedef __attribute__((ext_vector_type(4))) float  float4v;
typedef unsigned long long ull;

__device__ __forceinline__ short bf16s(float f) {            // RNE scalar (setup only)
  union { float ff; unsigned int u; } c; c.ff = f;
  return (short)((c.u + 0x7fffu + ((c.u >> 16) & 1u)) >> 16);
}

// table[v][g] = b_ih[g] + sum_e W_ih[g,e]*emb[v,e] (+ b_hh[g] for g<2H)
// r,z rows natural units (LUT takes u directly); n rows scaled by 2*log2e.
__global__ void gi_table_kernel(const float* __restrict__ emb,
                                const float* __restrict__ W_ih,
                                const float* __restrict__ b_ih,
                                const float* __restrict__ b_hh,
                                float* __restrict__ table) {
  int gid = blockIdx.x * blockDim.x + threadIdx.x;
  if (gid >= V_ * G3) return;
  int v = gid / G3;
  int g = gid - v * G3;
  float acc = b_ih[g];
  if (g < 2 * H_) acc += b_hh[g];
  const float* wr = W_ih + g * E_;
  const float* er = emb + v * E_;
#pragma unroll 8
  for (int e = 0; e < E_; ++e) acc += wr[e] * er[e];
  table[gid] = (g < 2 * H_) ? acc : acc * 2.f * LOG2E;
}

#define MFMA16(A, B, C) __builtin_amdgcn_mfma_f32_16x16x32_bf16((A), (B), (C), 0, 0, 0)

__global__ __launch_bounds__(512) void gru_kernel(
    const int* __restrict__ x, const float* __restrict__ W_hh,
    const float* __restrict__ b_hh, const float* __restrict__ W_fc,
    const float* __restrict__ b_fc, const float* __restrict__ table,
    float* __restrict__ out) {
  __shared__ __align__(16) short  hbuf[2][16 * SH];      // bf16 h, double-buffered
  __shared__ __align__(16) ull    ohbuf[TC * 16 + 32];   // one-hot per (t,row) + zero/pad
  __shared__ __align__(16) float  hf[16 * H_];           // epilogue fp32 h
  __shared__ __align__(8)  float2 lutS[LUTN];            // sigmoid PWL (slope, icpt)

  const int tid  = threadIdx.x;
  const int w    = tid >> 6;        // wave 0..7
  const int lane = tid & 63;
  const int m    = lane & 15;       // batch row (B/C col) and A gate-row
  const int q    = lane >> 4;       // quad
  const int g0   = blockIdx.x * 16;

  // ---- sigmoid LUT build (one entry per thread) ----
  if (tid < LUTN) {
    float x0 = -9.f + (float)tid * (18.f / 512.f);
    float x1 = x0 + (18.f / 512.f);
    float s0 = 1.f / (1.f + __expf(-x0));
    float s1 = 1.f / (1.f + __expf(-x1));
    float sl = (s1 - s0) * (512.f / 18.f);
    float2 c; c.x = sl; c.y = s0 - sl * x0;
    lutS[tid] = c;
  }

  // ---- persistent A-fragments: W_hh tiles, A[g=m][k=q*8+j] ----
  // r,z rows natural; n rows pre-scaled by 2*log2e.
  short8 wA[3][4];
#pragma unroll
  for (int s = 0; s < 3; ++s) {
    const float sc = (s < 2) ? 1.f : 2.f * LOG2E;
    const float* wrow = W_hh + (s * H_ + w * 16 + m) * H_;
#pragma unroll
    for (int ks = 0; ks < 4; ++ks) {
      const float* p = wrow + ks * 32 + q * 8;
      short8 f;
#pragma unroll
      for (int jj = 0; jj < 8; ++jj) f[jj] = bf16s(p[jj] * sc);
      wA[s][ks] = f;
    }
  }
  // table A-frags for the one-hot gi MFMA (q==0 lanes hold k'=0..3)
  short8 tabA[3];
#pragma unroll
  for (int s = 0; s < 3; ++s) {
    short8 f = {0, 0, 0, 0, 0, 0, 0, 0};
    if (q == 0) {
#pragma unroll
      for (int jj = 0; jj < 4; ++jj)
        f[jj] = bf16s(table[jj * G3 + s * H_ + w * 16 + m]);
    }
    tabA[s] = f;
  }

  const int c0 = w * 16 + q * 4;    // this lane's h-col base
  float4v bhnC;                     // a2 chain C-init: b_hh_n * 2log2e
  {
    const float* p = b_hh + 2 * H_ + c0;
#pragma unroll
    for (int i = 0; i < 4; ++i) bhnC[i] = p[i] * 2.f * LOG2E;
  }
  float h_old[4] = {0.f, 0.f, 0.f, 0.f};

  for (int i = tid; i < 16 * SH; i += 512) hbuf[0][i] = 0;   // h0 = 0
  if (tid == 0) ohbuf[ZIDX] = 0ull;

  const int  ohinc = (q == 0) ? 16 : 0;
  const float4v zero4 = {0.f, 0.f, 0.f, 0.f};
  ull ohcur = 0;      // software-pipelined one-hot payload (loaded 1 step ahead)
  int ohidx = 0;

  auto step = [&](int FROM, int TO) {
    // h reads (latency covered by one-hot MFMAs below)
    const short* rbp = &hbuf[FROM][m * SH + q * 8];
    short8 h0 = *(const short8*)(rbp);
    short8 h1 = *(const short8*)(rbp + 32);
    short8 h2 = *(const short8*)(rbp + 64);
    short8 h3 = *(const short8*)(rbp + 96);

    union { short8 s; ull u[2]; } ohf;
    ohf.u[0] = ohcur; ohf.u[1] = 0ull;
    float4v t0 = MFMA16(tabA[0], ohf.s, zero4);
    float4v t1 = MFMA16(tabA[1], ohf.s, zero4);
    float4v a3 = MFMA16(tabA[2], ohf.s, zero4);
    ohcur = ohbuf[ohidx];
    ohidx += ohinc;

    // a0/a1 as depth-3 dual chains; a2 serial depth-4 with bhnC C-init
    float4v a0 = MFMA16(wA[0][0], h0, t0);
    float4v a1 = MFMA16(wA[1][0], h0, t1);
    float4v a2 = MFMA16(wA[2][0], h0, bhnC);
    float4v b0 = MFMA16(wA[0][2], h2, zero4);
    float4v b1 = MFMA16(wA[1][2], h2, zero4);
    a0 = MFMA16(wA[0][1], h1, a0);
    a1 = MFMA16(wA[1][1], h1, a1);
    a2 = MFMA16(wA[2][1], h1, a2);
    b0 = MFMA16(wA[0][3], h3, b0);
    b1 = MFMA16(wA[1][3], h3, b1);
    a2 = MFMA16(wA[2][2], h2, a2);
    a2 = MFMA16(wA[2][3], h3, a2);

    // r,z via LDS LUT (full-rate VALU + LDS gather; no trans)
    float r[4], z[4];
#pragma unroll
    for (int i = 0; i < 4; ++i) {
      float ur = fminf(fmaxf(a0[i] + b0[i], UCLMIN), UCLMAX);
      float uz = fminf(fmaxf(a1[i] + b1[i], UCLMIN), UCLMAX);
      float fr = __fmaf_rn(ur, LSCALE, LOFF);
      float fz = __fmaf_rn(uz, LSCALE, LOFF);
      float2 cr = lutS[(unsigned)fr];
      float2 cz = lutS[(unsigned)fz];
      r[i] = __fmaf_rn(cr.x, ur, cr.y);
      z[i] = __fmaf_rn(cz.x, uz, cz.y);
    }
    // n via trans (short tail), h update, bf16 pack
    unsigned int rb_[4];
#pragma unroll
    for (int i = 0; i < 4; ++i) {
      float np = __fmaf_rn(r[i], a2[i], a3[i]);      // a2 includes bhn, all *2log2e
      float e2 = __builtin_amdgcn_exp2f(np);
      float nn = __fmaf_rn(-2.f, __builtin_amdgcn_rcpf(e2 + 1.f), 1.f);
      float hn = __fmaf_rn(z[i], h_old[i] - nn, nn);
      h_old[i] = hn;
      union { float ff; unsigned int u; } c; c.ff = hn;
      rb_[i] = c.u + 0x8000u;                        // round-half-up to bf16
    }
    unsigned int pk0 = __builtin_amdgcn_perm(rb_[1], rb_[0], 0x07060302u);
    unsigned int pk1 = __builtin_amdgcn_perm(rb_[3], rb_[2], 0x07060302u);
    *(ull*)(&hbuf[TO][m * SH + c0]) = ((ull)pk1 << 32) | pk0;
    __syncthreads();
  };

  for (int c = 0; c < 4; ++c) {
    // ---- refill one-hot staging for this 128-step chunk ----
    {
      int mm = tid >> 5, u = tid & 31;
      int4 xv = *(const int4*)(x + (g0 + mm) * T_ + c * TC + u * 4);
      int vs[4] = {xv.x, xv.y, xv.z, xv.w};
#pragma unroll
      for (int e = 0; e < 4; ++e) {
        int v = vs[e] & 3;
        unsigned int d0 = (v == 0) ? 0x3F80u : (v == 1) ? 0x3F800000u : 0u;
        unsigned int d1 = (v == 2) ? 0x3F80u : (v == 3) ? 0x3F800000u : 0u;
        ohbuf[(u * 4 + e) * 16 + mm] = ((ull)d1 << 32) | d0;
      }
    }
    __syncthreads();
    ohidx = (q == 0) ? m : ZIDX;
    ohcur = ohbuf[ohidx];           // preload step 0 of this chunk
    ohidx += ohinc;
    for (int tc = 0; tc < TC; tc += 2) {
      step(0, 1);
      step(1, 0);
    }
  }

  // ---- epilogue: logits = hT @ W_fc^T + b_fc ----
  float4v hv;
#pragma unroll
  for (int i = 0; i < 4; ++i) hv[i] = h_old[i];
  *(float4v*)(&hf[m * H_ + c0]) = hv;
  __syncthreads();

  if (tid < 64) {
    int row = tid >> 2, vo = tid & 3;
    float s = b_fc[vo];
    const float* wv = W_fc + vo * H_;
    const float* hr = &hf[row * H_];
#pragma unroll 4
    for (int k = 0; k < H_; k += 4)
      s += hr[k] * wv[k] + hr[k + 1] * wv[k + 1]
         + hr[k + 2] * wv[k + 2] + hr[k + 3] * wv[k + 3];
    out[(g0 + row) * V_ + vo] = s;
  }
}

extern "C" void kernel_launch(void* const* d_in, const int* in_sizes, int n_in,
                              void* d_out, int out_size, void* d_ws, size_t ws_size,
                              hipStream_t stream) {
  const int*   x    = (const int*)d_in[0];
  const float* emb  = (const float*)d_in[1];
  const float* W_ih = (const float*)d_in[2];
  const float* W_hh = (const float*)d_in[3];
  const float* b_ih = (const float*)d_in[4];
  const float* b_hh = (const float*)d_in[5];
  const float* W_fc = (const float*)d_in[6];
  const float* b_fc = (const float*)d_in[7];
  float* out   = (float*)d_out;
  float* table = (float*)d_ws;     // 4*384 fp32 = 6 KB

  gi_table_kernel<<<(V_ * G3 + 255) / 256, 256, 0, stream>>>(emb, W_ih, b_ih, b_hh, table);
  gru_kernel<<<B_ / 16, 512, 0, stream>>>(x, W_hh, b_hh, W_fc, b_fc, table, out);
}

// Round 7
// 353.003 us; speedup vs baseline: 1.1132x; 1.1132x over previous
//
#include <hip/hip_runtime.h>
#include <hip/hip_bf16.h>

// GRU policy: B=2048, T=512, V=4, E=64, H=128.
// R6 (base = R2/R4 309us structure; R5 LUT reverted — it added gather latency
//     to the loop-carried path):
//  (1) one-hot MFMAs removed: gi(t) preloaded one step ahead as 3 fp32
//      ds_read_b128 from LDS table (h-independent -> latency hidden behind
//      previous step's epilogue+barrier). gi_r/gi_z are MFMA C-inits, gi_n a
//      register operand. 15 -> 12 MFMA/wave-step (-116 cyc matrix/SIMD-step).
//  (2) chains issued in consumption order a0 -> a2 -> a1 with gate VALU
//      interleaved: r under a2 drain, np/tanh under a1 drain; only z-sigmoid
//      + blend/pack after the last MFMA.
//  (3) ohbuf machinery dropped; x staged once as bytes, token byte preloaded
//      2 steps ahead.
// Per wave/step: 12 MFMA, 4 ds_read_b128 (h) + 3 ds_read_b128 (gi, next) +
// 1 ds_read_u8 + 1 ds_write_b64, 24 trans. 1 barrier/step. 128 blocks
// (structural: MFMA M=16 granularity, B/16).

#define B_  2048
#define T_  512
#define V_  4
#define E_  64
#define H_  128
#define G3  384
#define SH  136            // h row stride (bf16 elems)

#define LOG2E 1.4426950408889634f

typedef __attribute__((ext_vector_type(8))) short  short8;   // 8 bf16
typedef __attribute__((ext_vector_type(4))) float  float4v;
typedef unsigned long long ull;

__device__ __forceinline__ short bf16s(float f) {            // RNE scalar (setup only)
  union { float ff; unsigned int u; } c; c.ff = f;
  return (short)((c.u + 0x7fffu + ((c.u >> 16) & 1u)) >> 16);
}

// table[v][g] = scale_g * (b_ih[g] + sum_e W_ih[g,e]*emb[v,e] (+ b_hh[g] for g<2H))
// scale_g = -log2e for r,z rows; +2*log2e for n rows (b_hh_n NOT folded).
__global__ void gi_table_kernel(const float* __restrict__ emb,
                                const float* __restrict__ W_ih,
                                const float* __restrict__ b_ih,
                                const float* __restrict__ b_hh,
                                float* __restrict__ table) {
  int gid = blockIdx.x * blockDim.x + threadIdx.x;
  if (gid >= V_ * G3) return;
  int v = gid / G3;
  int g = gid - v * G3;
  float acc = b_ih[g];
  if (g < 2 * H_) acc += b_hh[g];
  const float* wr = W_ih + g * E_;
  const float* er = emb + v * E_;
#pragma unroll 8
  for (int e = 0; e < E_; ++e) acc += wr[e] * er[e];
  table[gid] = acc * ((g < 2 * H_) ? -LOG2E : 2.f * LOG2E);
}

#define MFMA16(A, B, C) __builtin_amdgcn_mfma_f32_16x16x32_bf16((A), (B), (C), 0, 0, 0)

__global__ __launch_bounds__(512) void gru_kernel(
    const int* __restrict__ x, const float* __restrict__ W_hh,
    const float* __restrict__ b_hh, const float* __restrict__ W_fc,
    const float* __restrict__ b_fc, const float* __restrict__ table,
    float* __restrict__ out) {
  __shared__ __align__(16) short hbuf[2][16 * SH];          // bf16 h, double-buffered
  __shared__ __align__(16) unsigned char xs[(T_ + 2) * 16]; // tokens [t][row], 2 pad rows
  __shared__ __align__(16) float tabS[V_ * G3];             // gi table (pre-scaled)
  __shared__ __align__(16) float hf[16 * H_];               // epilogue fp32 h

  const int tid  = threadIdx.x;
  const int w    = tid >> 6;        // wave 0..7
  const int lane = tid & 63;
  const int m    = lane & 15;       // batch row (B/C col) and A gate-row
  const int q    = lane >> 4;       // quad
  const int g0   = blockIdx.x * 16;

  // ---- stage x -> xs[t][r] bytes; zero the 2 pad rows ----
  for (int i = tid; i < 16 * T_; i += 512) {
    int r = i >> 9;                 // 0..15
    int t = i & (T_ - 1);
    xs[t * 16 + r] = (unsigned char)(x[(g0 + r) * T_ + t] & 3);
  }
  if (tid < 32) xs[T_ * 16 + tid] = 0;
  // ---- stage gi table to LDS ----
  for (int i = tid; i < V_ * G3; i += 512) tabS[i] = table[i];
  // ---- h0 = 0 ----
  for (int i = tid; i < 16 * SH; i += 512) hbuf[0][i] = 0;

  // ---- persistent A-fragments: W_hh tiles (pre-scaled), A[g=m][k=q*8+j] ----
  short8 wA[3][4];
#pragma unroll
  for (int s = 0; s < 3; ++s) {
    const float sc = (s < 2) ? -LOG2E : 2.f * LOG2E;
    const float* wrow = W_hh + (s * H_ + w * 16 + m) * H_;
#pragma unroll
    for (int ks = 0; ks < 4; ++ks) {
      const float* p = wrow + ks * 32 + q * 8;
      short8 f;
#pragma unroll
      for (int jj = 0; jj < 8; ++jj) f[jj] = bf16s(p[jj] * sc);
      wA[s][ks] = f;
    }
  }

  const int c0 = w * 16 + q * 4;    // this lane's h-col base
  float4v bhnC;                     // a2 chain C-init: b_hh_n * 2log2e
  {
    const float* p = b_hh + 2 * H_ + c0;
#pragma unroll
    for (int i = 0; i < 4; ++i) bhnC[i] = p[i] * 2.f * LOG2E;
  }
  float h_old[4] = {0.f, 0.f, 0.f, 0.f};

  __syncthreads();

  // ---- prologue: gi(0) + token byte of t=1 ----
  float4v giR, giZ, giN;
  int vb1;
  {
    int v0 = xs[m] & 3;
    const float* tb = &tabS[v0 * G3 + c0];
    giR = *(const float4v*)(tb);
    giZ = *(const float4v*)(tb + H_);
    giN = *(const float4v*)(tb + 2 * H_);
    vb1 = xs[16 + m];
  }

  auto step = [&](int FROM, int TO, int t) {
    // h fragments (latency partially hidden by gi preloads' independence)
    const short* rbp = &hbuf[FROM][m * SH + q * 8];
    short8 h0 = *(const short8*)(rbp);
    short8 h1 = *(const short8*)(rbp + 32);
    short8 h2 = *(const short8*)(rbp + 64);
    short8 h3 = *(const short8*)(rbp + 96);

    // issue next-step preloads early (h-independent; consumed next step)
    int vb2 = xs[(t + 2) * 16 + m];
    const float* tbn = &tabS[(vb1 & 3) * G3 + c0];
    float4v giRn = *(const float4v*)(tbn);
    float4v giZn = *(const float4v*)(tbn + H_);
    float4v giNn = *(const float4v*)(tbn + 2 * H_);

    // a0 (r) chain first — r is on the serial path through np
    float4v a0 = MFMA16(wA[0][0], h0, giR);
    a0 = MFMA16(wA[0][1], h1, a0);
    a0 = MFMA16(wA[0][2], h2, a0);
    a0 = MFMA16(wA[0][3], h3, a0);
    // a2 (n-gh) chain; r computed under its drain
    float4v a2 = MFMA16(wA[2][0], h0, bhnC);
    a2 = MFMA16(wA[2][1], h1, a2);
    float r0 = __builtin_amdgcn_rcpf(1.f + __builtin_amdgcn_exp2f(a0[0]));
    float r1 = __builtin_amdgcn_rcpf(1.f + __builtin_amdgcn_exp2f(a0[1]));
    float r2 = __builtin_amdgcn_rcpf(1.f + __builtin_amdgcn_exp2f(a0[2]));
    float r3 = __builtin_amdgcn_rcpf(1.f + __builtin_amdgcn_exp2f(a0[3]));
    a2 = MFMA16(wA[2][2], h2, a2);
    a2 = MFMA16(wA[2][3], h3, a2);
    // a1 (z) chain last; np/tanh computed under its drain
    float4v a1 = MFMA16(wA[1][0], h0, giZ);
    a1 = MFMA16(wA[1][1], h1, a1);
    float nn[4];
    {
      float np0 = __fmaf_rn(r0, a2[0], giN[0]);
      float np1 = __fmaf_rn(r1, a2[1], giN[1]);
      float np2 = __fmaf_rn(r2, a2[2], giN[2]);
      float np3 = __fmaf_rn(r3, a2[3], giN[3]);
      nn[0] = __fmaf_rn(-2.f, __builtin_amdgcn_rcpf(__builtin_amdgcn_exp2f(np0) + 1.f), 1.f);
      nn[1] = __fmaf_rn(-2.f, __builtin_amdgcn_rcpf(__builtin_amdgcn_exp2f(np1) + 1.f), 1.f);
      nn[2] = __fmaf_rn(-2.f, __builtin_amdgcn_rcpf(__builtin_amdgcn_exp2f(np2) + 1.f), 1.f);
      nn[3] = __fmaf_rn(-2.f, __builtin_amdgcn_rcpf(__builtin_amdgcn_exp2f(np3) + 1.f), 1.f);
    }
    a1 = MFMA16(wA[1][2], h2, a1);
    a1 = MFMA16(wA[1][3], h3, a1);
    // z, blend, pack, write — the only post-matrix tail
    unsigned int rb_[4];
#pragma unroll
    for (int i = 0; i < 4; ++i) {
      float z  = __builtin_amdgcn_rcpf(1.f + __builtin_amdgcn_exp2f(a1[i]));
      float hn = __fmaf_rn(z, h_old[i] - nn[i], nn[i]);
      h_old[i] = hn;
      union { float ff; unsigned int u; } c; c.ff = hn;
      rb_[i] = c.u + 0x8000u;                        // round-half-up to bf16
    }
    unsigned int pk0 = __builtin_amdgcn_perm(rb_[1], rb_[0], 0x07060302u);
    unsigned int pk1 = __builtin_amdgcn_perm(rb_[3], rb_[2], 0x07060302u);
    *(ull*)(&hbuf[TO][m * SH + c0]) = ((ull)pk1 << 32) | pk0;
    // rotate preloads
    giR = giRn; giZ = giZn; giN = giNn; vb1 = vb2;
    __syncthreads();
  };

  for (int t = 0; t < T_; t += 2) {
    step(0, 1, t);
    step(1, 0, t + 1);
  }

  // ---- epilogue: logits = hT @ W_fc^T + b_fc ----
  float4v hv;
#pragma unroll
  for (int i = 0; i < 4; ++i) hv[i] = h_old[i];
  *(float4v*)(&hf[m * H_ + c0]) = hv;
  __syncthreads();

  if (tid < 64) {
    int row = tid >> 2, vo = tid & 3;
    float s = b_fc[vo];
    const float* wv = W_fc + vo * H_;
    const float* hr = &hf[row * H_];
#pragma unroll 4
    for (int k = 0; k < H_; k += 4)
      s += hr[k] * wv[k] + hr[k + 1] * wv[k + 1]
         + hr[k + 2] * wv[k + 2] + hr[k + 3] * wv[k + 3];
    out[(g0 + row) * V_ + vo] = s;
  }
}

extern "C" void kernel_launch(void* const* d_in, const int* in_sizes, int n_in,
                              void* d_out, int out_size, void* d_ws, size_t ws_size,
                              hipStream_t stream) {
  const int*   x    = (const int*)d_in[0];
  const float* emb  = (const float*)d_in[1];
  const float* W_ih = (const float*)d_in[2];
  const float* W_hh = (const float*)d_in[3];
  const float* b_ih = (const float*)d_in[4];
  const float* b_hh = (const float*)d_in[5];
  const float* W_fc = (const float*)d_in[6];
  const float* b_fc = (const float*)d_in[7];
  float* out   = (float*)d_out;
  float* table = (float*)d_ws;     // 4*384 fp32 = 6 KB

  gi_table_kernel<<<(V_ * G3 + 255) / 256, 256, 0, stream>>>(emb, W_ih, b_ih, b_hh, table);
  gru_kernel<<<B_ / 16, 512, 0, stream>>>(x, W_hh, b_hh, W_fc, b_fc, table, out);
}